// Round 14
// baseline (818.750 us; speedup 1.0000x reference)
//
#include <hip/hip_runtime.h>
#include <hip/hip_bf16.h>
#include <cmath>

typedef __attribute__((ext_vector_type(4))) float f32x4;
typedef __attribute__((ext_vector_type(8))) short s16x8;
typedef __attribute__((ext_vector_type(4))) short s16x4;
typedef __attribute__((ext_vector_type(4))) unsigned short u16x4;

static constexpr int NCOL = 512;    // L
static constexpr int NBATCH = 1024; // 32*32
static constexpr int SLOT = 64 * NCOL;     // floats per batch slot
static constexpr int GOFF = 16384;         // G region: floats [16384, 20480)

__device__ inline unsigned short bf16h(float f) {
  return __builtin_bit_cast(unsigned short, __float2bfloat16(f));
}
__device__ inline float bf16f(unsigned short h) {
  unsigned u = ((unsigned)h) << 16;
  return __builtin_bit_cast(float, u);
}

// 8B-aligned s16x8 load (XT rows at stride 68 ushorts are only 8B-aligned)
__device__ inline s16x8 ld8(const unsigned short* p) {
  const s16x4 a = *(const s16x4*)(p);
  const s16x4 b = *(const s16x4*)(p + 4);
  s16x8 r;
  r[0]=a[0]; r[1]=a[1]; r[2]=a[2]; r[3]=a[3];
  r[4]=b[0]; r[5]=b[1]; r[6]=b[2]; r[7]=b[3];
  return r;
}

// Kernel 1: per-batch G = X X^T via bf16 hi/lo MFMA.  Lean (18.4 KB LDS,
// ~60 VGPR -> 8 blocks/CU).  G accumulators store to the slot's G region.
__global__ __launch_bounds__(256) void gs_gram_kernel(const float* __restrict__ x,
                                                      float* __restrict__ outbuf)
{
  __shared__ unsigned short Hs[64][72];
  __shared__ unsigned short Ls[64][72];

  const int b = blockIdx.x;
  const int t = threadIdx.x;
  const int lane = t & 63;
  const int w = t >> 6;

  const float* __restrict__ X = x + (size_t)b * SLOT;

  f32x4 acc[4];
#pragma unroll
  for (int j = 0; j < 4; ++j) { acc[j][0] = 0.f; acc[j][1] = 0.f; acc[j][2] = 0.f; acc[j][3] = 0.f; }

  const int lrow = t >> 4;               // 0..15
  const int lcol = (t & 15) * 4;
  const int frow = lane & 15;
  const int fk   = (lane >> 4) * 8;

  for (int ch = 0; ch < 8; ++ch) {
    __syncthreads();
#pragma unroll
    for (int p = 0; p < 4; ++p) {
      const int r = lrow + 16 * p;
      const f32x4 v = *(const f32x4*)(X + (size_t)r * NCOL + ch * 64 + lcol);
      u16x4 hv, lv;
#pragma unroll
      for (int j = 0; j < 4; ++j) {
        const unsigned short h = bf16h(v[j]);
        hv[j] = h;
        lv[j] = bf16h(v[j] - bf16f(h));
      }
      *(u16x4*)&Hs[r][lcol] = hv;
      *(u16x4*)&Ls[r][lcol] = lv;
    }
    __syncthreads();
#pragma unroll
    for (int s = 0; s < 2; ++s) {
      const int kc = s * 32 + fk;
      const s16x8 ha = *(const s16x8*)&Hs[16 * w + frow][kc];
      const s16x8 la = *(const s16x8*)&Ls[16 * w + frow][kc];
#pragma unroll
      for (int bt = 0; bt < 4; ++bt) {
        const s16x8 hb = *(const s16x8*)&Hs[16 * bt + frow][kc];
        const s16x8 lb = *(const s16x8*)&Ls[16 * bt + frow][kc];
        acc[bt] = __builtin_amdgcn_mfma_f32_16x16x32_bf16(ha, hb, acc[bt], 0, 0, 0);
        acc[bt] = __builtin_amdgcn_mfma_f32_16x16x32_bf16(ha, lb, acc[bt], 0, 0, 0);
        acc[bt] = __builtin_amdgcn_mfma_f32_16x16x32_bf16(la, hb, acc[bt], 0, 0, 0);
      }
    }
  }

  // C/D layout: col = lane&15, row = (lane>>4)*4 + reg
  float* __restrict__ Gs = outbuf + (size_t)b * SLOT + GOFF;
  const int drow = (lane >> 4) * 4;
  const int dcol = lane & 15;
#pragma unroll
  for (int bt = 0; bt < 4; ++bt)
#pragma unroll
    for (int rr = 0; rr < 4; ++rr)
      Gs[(16 * w + drow + rr) * 64 + 16 * bt + dcol] = acc[bt][rr];
}

// Kernel 2: one wave per batch, ALL-REGISTER solve (zero LDS).  Lane j
// holds W-row j; cross-lane via __shfl only.  Register budget fix vs the
// 256-VGPR spill (round 13): inv[64] replaced by ONE per-lane register
// (lane k holds 1/sqrt(n_k)); the inverse itself is consumed immediately.
// Peak live ~= w[64]+u[64] (LDL) and u[64]+ti[64] (TI) ~= 130 VGPR.
__global__ __launch_bounds__(64) void gs_solve_kernel(float* __restrict__ outbuf)
{
  const int b = blockIdx.x;
  const int j = threadIdx.x;             // lane
  float* __restrict__ slot = outbuf + (size_t)b * SLOT;
  const float* __restrict__ Gs = slot + GOFF;

  // W-row j of G into registers (L2-hot, 16 KB/batch)
  float w[64];
#pragma unroll
  for (int c = 0; c < 16; ++c) {
    const f32x4 v = *(const f32x4*)(Gs + j * 64 + 4 * c);
    w[4 * c + 0] = v[0]; w[4 * c + 1] = v[1]; w[4 * c + 2] = v[2]; w[4 * c + 3] = v[3];
  }

  float u[64];          // u[m] = Cs[j][m] (lane-local scaled coefficient row)
  float myisn = 0.0f;   // lane k holds 1/sqrt(n_k)
  {
    const float n0 = __shfl(w[0], 0);
    const float inv0 = 1.0f / n0;
    u[0] = w[0] * inv0;
    if (j == 0) myisn = sqrtf(inv0);
  }
#pragma unroll
  for (int k = 1; k < 64; ++k) {
    float s0 = 0.f, s1 = 0.f, s2 = 0.f, s3 = 0.f;
#pragma unroll
    for (int m = 0; m < k; ++m) {
      const float ckm = __shfl(u[m], k);   // Cs[k][m], uniform broadcast
      const float p = ckm * w[m];
      if ((m & 3) == 0) s0 += p;
      else if ((m & 3) == 1) s1 += p;
      else if ((m & 3) == 2) s2 += p;
      else s3 += p;
    }
    w[k] -= (s0 + s1) + (s2 + s3);
    const float nk = __shfl(w[k], k);
    const float invk = 1.0f / nk;          // uniform; consumed immediately
    u[k] = w[k] * invk;
    if (j == k) myisn = sqrtf(invk);
  }

  // TI: lane j owns column j: ti[i] = d(i,j) - sum_{m<i} Cs[i][m]*ti[m]
  float ti[64];
  ti[0] = (j == 0) ? 1.0f : 0.0f;
#pragma unroll
  for (int i = 1; i < 64; ++i) {
    float s0 = 0.f, s1 = 0.f, s2 = 0.f, s3 = 0.f;
#pragma unroll
    for (int m = 0; m < i; ++m) {
      const float cim = __shfl(u[m], i);   // Cs[i][m], uniform broadcast
      const float p = cim * ti[m];
      if ((m & 3) == 0) s0 += p;
      else if ((m & 3) == 1) s1 += p;
      else if ((m & 3) == 2) s2 += p;
      else s3 += p;
    }
    ti[i] = ((i == j) ? 1.0f : 0.0f) - ((s0 + s1) + (s2 + s3));
  }

  // emit planar: u16 [0,4096) = Th, [4096,8192) = Tl; lanes coalesce per row
  unsigned short* __restrict__ slotU = (unsigned short*)slot;
#pragma unroll
  for (int i = 0; i < 64; ++i) {
    const float isn_i = __shfl(myisn, i);
    const float tf = isn_i * ti[i];
    const unsigned short h = bf16h(tf);
    slotU[i * 64 + j] = h;
    slotU[4096 + i * 64 + j] = bf16h(tf - bf16f(h));
  }
}

// Kernel 3: out = T * X per batch, pure MFMA.  T fragments loaded directly
// from global (planar slot head, L2/L3-hot).  17.4 KB LDS.
__global__ __launch_bounds__(256) void gs_apply_kernel(const float* __restrict__ x,
                                                       float* __restrict__ outbuf)
{
  __shared__ unsigned short XTh[64][68];
  __shared__ unsigned short XTl[64][68];

  const int b = blockIdx.x;
  const int t = threadIdx.x;
  const int lane = t & 63;
  const int w = t >> 6;

  float* __restrict__ slot = outbuf + (size_t)b * SLOT;
  const unsigned short* __restrict__ slotU = (const unsigned short*)slot;

  const int frow = lane & 15;
  const int fk = (lane >> 4) * 8;

  // A-operand fragments straight from global: planar Th/Tl rows
  s16x8 tah[2], tal[2];
#pragma unroll
  for (int ks = 0; ks < 2; ++ks) {
    tah[ks] = *(const s16x8*)&slotU[(16 * w + frow) * 64 + ks * 32 + fk];
    tal[ks] = *(const s16x8*)&slotU[4096 + (16 * w + frow) * 64 + ks * 32 + fk];
  }
  __syncthreads();   // vmcnt drained at barrier: T loads landed before any store

  const float* __restrict__ X = x + (size_t)b * SLOT;
  const int lrow4 = (t >> 4) * 4;
  const int lcol4 = (t & 15) * 4;

  for (int ch = 0; ch < 8; ++ch) {
    if (ch) __syncthreads();             // protect XT from prev-chunk readers
    float vr[4][4];
#pragma unroll
    for (int p = 0; p < 4; ++p) {
      const f32x4 v = *(const f32x4*)(X + (size_t)(lrow4 + p) * NCOL + ch * 64 + lcol4);
      vr[p][0] = v[0]; vr[p][1] = v[1]; vr[p][2] = v[2]; vr[p][3] = v[3];
    }
#pragma unroll
    for (int jj = 0; jj < 4; ++jj) {
      u16x4 hv, lv;
#pragma unroll
      for (int p = 0; p < 4; ++p) {
        const unsigned short h = bf16h(vr[p][jj]);
        hv[p] = h;
        lv[p] = bf16h(vr[p][jj] - bf16f(h));
      }
      *(u16x4*)&XTh[lcol4 + jj][lrow4] = hv;
      *(u16x4*)&XTl[lcol4 + jj][lrow4] = lv;
    }
    __syncthreads();

    f32x4 oacc[4];
#pragma unroll
    for (int q = 0; q < 4; ++q) { oacc[q][0] = 0.f; oacc[q][1] = 0.f; oacc[q][2] = 0.f; oacc[q][3] = 0.f; }

#pragma unroll
    for (int ks = 0; ks < 2; ++ks) {
      const int kc = ks * 32 + fk;
#pragma unroll
      for (int ct = 0; ct < 4; ++ct) {
        const s16x8 xbh = ld8(&XTh[ct * 16 + frow][kc]);
        const s16x8 xbl = ld8(&XTl[ct * 16 + frow][kc]);
        oacc[ct] = __builtin_amdgcn_mfma_f32_16x16x32_bf16(tah[ks], xbh, oacc[ct], 0, 0, 0);
        oacc[ct] = __builtin_amdgcn_mfma_f32_16x16x32_bf16(tah[ks], xbl, oacc[ct], 0, 0, 0);
        oacc[ct] = __builtin_amdgcn_mfma_f32_16x16x32_bf16(tal[ks], xbh, oacc[ct], 0, 0, 0);
      }
    }

    const int drow = (lane >> 4) * 4;
    const int dcol = lane & 15;
#pragma unroll
    for (int ct = 0; ct < 4; ++ct)
#pragma unroll
      for (int rr = 0; rr < 4; ++rr)
        slot[(size_t)(16 * w + drow + rr) * NCOL + ch * 64 + ct * 16 + dcol] = oacc[ct][rr];
  }
}

extern "C" void kernel_launch(void* const* d_in, const int* in_sizes, int n_in,
                              void* d_out, int out_size, void* d_ws, size_t ws_size,
                              hipStream_t stream) {
  const float* x = (const float*)d_in[0];
  float* out = (float*)d_out;
  gs_gram_kernel<<<NBATCH, 256, 0, stream>>>(x, out);
  gs_solve_kernel<<<NBATCH, 64, 0, stream>>>(out);
  gs_apply_kernel<<<NBATCH, 256, 0, stream>>>(x, out);
}

// Round 15
// 372.226 us; speedup vs baseline: 2.1996x; 2.1996x over previous
//
#include <hip/hip_runtime.h>
#include <hip/hip_bf16.h>
#include <cmath>

typedef __attribute__((ext_vector_type(4))) float f32x4;
typedef __attribute__((ext_vector_type(8))) short s16x8;
typedef __attribute__((ext_vector_type(4))) short s16x4;
typedef __attribute__((ext_vector_type(4))) unsigned short u16x4;

static constexpr int NCOL = 512;    // L
static constexpr int NBATCH = 1024; // 32*32
static constexpr int SLOT = 64 * NCOL;     // floats per batch slot
static constexpr int GOFF = 16384;         // G region: floats [16384, 20480)

__device__ inline unsigned short bf16h(float f) {
  return __builtin_bit_cast(unsigned short, __float2bfloat16(f));
}
__device__ inline float bf16f(unsigned short h) {
  unsigned u = ((unsigned)h) << 16;
  return __builtin_bit_cast(float, u);
}

// 8B-aligned s16x8 load (XT rows at stride 68 ushorts are only 8B-aligned)
__device__ inline s16x8 ld8(const unsigned short* p) {
  const s16x4 a = *(const s16x4*)(p);
  const s16x4 b = *(const s16x4*)(p + 4);
  s16x8 r;
  r[0]=a[0]; r[1]=a[1]; r[2]=a[2]; r[3]=a[3];
  r[4]=b[0]; r[5]=b[1]; r[6]=b[2]; r[7]=b[3];
  return r;
}

// Kernel 1: per-batch G = X X^T via bf16 hi/lo MFMA.  Lean (18.4 KB LDS,
// ~60 VGPR -> 8 blocks/CU).  G accumulators store to the slot's G region.
__global__ __launch_bounds__(256) void gs_gram_kernel(const float* __restrict__ x,
                                                      float* __restrict__ outbuf)
{
  __shared__ unsigned short Hs[64][72];
  __shared__ unsigned short Ls[64][72];

  const int b = blockIdx.x;
  const int t = threadIdx.x;
  const int lane = t & 63;
  const int w = t >> 6;

  const float* __restrict__ X = x + (size_t)b * SLOT;

  f32x4 acc[4];
#pragma unroll
  for (int j = 0; j < 4; ++j) { acc[j][0] = 0.f; acc[j][1] = 0.f; acc[j][2] = 0.f; acc[j][3] = 0.f; }

  const int lrow = t >> 4;               // 0..15
  const int lcol = (t & 15) * 4;
  const int frow = lane & 15;
  const int fk   = (lane >> 4) * 8;

  for (int ch = 0; ch < 8; ++ch) {
    __syncthreads();
#pragma unroll
    for (int p = 0; p < 4; ++p) {
      const int r = lrow + 16 * p;
      const f32x4 v = *(const f32x4*)(X + (size_t)r * NCOL + ch * 64 + lcol);
      u16x4 hv, lv;
#pragma unroll
      for (int j = 0; j < 4; ++j) {
        const unsigned short h = bf16h(v[j]);
        hv[j] = h;
        lv[j] = bf16h(v[j] - bf16f(h));
      }
      *(u16x4*)&Hs[r][lcol] = hv;
      *(u16x4*)&Ls[r][lcol] = lv;
    }
    __syncthreads();
#pragma unroll
    for (int s = 0; s < 2; ++s) {
      const int kc = s * 32 + fk;
      const s16x8 ha = *(const s16x8*)&Hs[16 * w + frow][kc];
      const s16x8 la = *(const s16x8*)&Ls[16 * w + frow][kc];
#pragma unroll
      for (int bt = 0; bt < 4; ++bt) {
        const s16x8 hb = *(const s16x8*)&Hs[16 * bt + frow][kc];
        const s16x8 lb = *(const s16x8*)&Ls[16 * bt + frow][kc];
        acc[bt] = __builtin_amdgcn_mfma_f32_16x16x32_bf16(ha, hb, acc[bt], 0, 0, 0);
        acc[bt] = __builtin_amdgcn_mfma_f32_16x16x32_bf16(ha, lb, acc[bt], 0, 0, 0);
        acc[bt] = __builtin_amdgcn_mfma_f32_16x16x32_bf16(la, hb, acc[bt], 0, 0, 0);
      }
    }
  }

  // C/D layout: col = lane&15, row = (lane>>4)*4 + reg
  float* __restrict__ Gs = outbuf + (size_t)b * SLOT + GOFF;
  const int drow = (lane >> 4) * 4;
  const int dcol = lane & 15;
#pragma unroll
  for (int bt = 0; bt < 4; ++bt)
#pragma unroll
    for (int rr = 0; rr < 4; ++rr)
      Gs[(16 * w + drow + rr) * 64 + 16 * bt + dcol] = acc[bt][rr];
}

// Kernel 2: one wave per batch, FUSED LDL + triangular-inverse solve.
// Lane j holds W-row j (wr[]) and TI-column j (ti[]) in registers; the
// scaled coefficient matrix Cs lives in LDS (column k written at step k,
// row k read back as uniform broadcasts).  TI row k uses EXACTLY the same
// Cs[k][m] broadcasts as LDL step k -> one pass, half the LDS reads, two
// independent FMA chains under the same LDS latency.
//   LDL: W[j][k] -= sum_{m<k} Cs[k][m]*W[j][m];  Cs[j][k] = W[j][k]/n_k
//   TI:  ti[k] = d(k,j) - sum_{m<k} Cs[k][m]*ti[m]
// Emits T = diag(1/sqrt(n)) * (I+C)^{-1} planar bf16 hi/lo to slot head.
__global__ __launch_bounds__(64) void gs_solve_kernel(float* __restrict__ outbuf)
{
  __shared__ float Cs[64][68];
  __shared__ float ISN[64];

  const int b = blockIdx.x;
  const int j = threadIdx.x;             // lane
  float* __restrict__ slot = outbuf + (size_t)b * SLOT;
  const float* __restrict__ Gs = slot + GOFF;

  // W-row j of G into registers (L2-hot, 16 KB/batch)
  float wr[64];
#pragma unroll
  for (int c = 0; c < 16; ++c) {
    const f32x4 v = *(const f32x4*)(Gs + j * 64 + 4 * c);
    wr[4 * c + 0] = v[0]; wr[4 * c + 1] = v[1]; wr[4 * c + 2] = v[2]; wr[4 * c + 3] = v[3];
  }

  float ti[64];
  {
    const float n0 = __shfl(wr[0], 0);
    const float inv = 1.0f / n0;
    Cs[j][0] = wr[0] * inv;
    if (j == 0) ISN[0] = sqrtf(inv);
    ti[0] = (j == 0) ? 1.0f : 0.0f;      // TI row 0 = e0
  }
#pragma unroll
  for (int k = 1; k < 64; ++k) {
    float a0 = 0.f, a1 = 0.f, a2 = 0.f, a3 = 0.f;   // LDL accum
    float b0 = 0.f, b1 = 0.f, b2 = 0.f, b3 = 0.f;   // TI accum
    const int K4 = k >> 2;
#pragma unroll
    for (int m4 = 0; m4 < K4; ++m4) {
      const f32x4 c4 = *(const f32x4*)&Cs[k][4 * m4];   // uniform broadcast
      a0 += c4[0] * wr[4 * m4 + 0];
      a1 += c4[1] * wr[4 * m4 + 1];
      a2 += c4[2] * wr[4 * m4 + 2];
      a3 += c4[3] * wr[4 * m4 + 3];
      b0 += c4[0] * ti[4 * m4 + 0];
      b1 += c4[1] * ti[4 * m4 + 1];
      b2 += c4[2] * ti[4 * m4 + 2];
      b3 += c4[3] * ti[4 * m4 + 3];
    }
#pragma unroll
    for (int m = 4 * K4; m < k; ++m) {
      const float c = Cs[k][m];
      a0 += c * wr[m];
      b0 += c * ti[m];
    }
    wr[k] -= (a0 + a1) + (a2 + a3);
    const float nk = __shfl(wr[k], k);
    const float inv = 1.0f / nk;
    Cs[j][k] = wr[k] * inv;
    if (j == 0) ISN[k] = sqrtf(inv);
    ti[k] = ((k == j) ? 1.0f : 0.0f) - ((b0 + b1) + (b2 + b3));
  }

  // emit planar: u16 [0,4096) = Th, [4096,8192) = Tl; lanes coalesce per row
  unsigned short* __restrict__ slotU = (unsigned short*)slot;
#pragma unroll
  for (int i = 0; i < 64; ++i) {
    const float tf = ISN[i] * ti[i];
    const unsigned short h = bf16h(tf);
    slotU[i * 64 + j] = h;
    slotU[4096 + i * 64 + j] = bf16h(tf - bf16f(h));
  }
}

// Kernel 3: out = T * X per batch, pure MFMA.  T fragments loaded directly
// from global (planar slot head, L2/L3-hot).  17.4 KB LDS.
__global__ __launch_bounds__(256) void gs_apply_kernel(const float* __restrict__ x,
                                                       float* __restrict__ outbuf)
{
  __shared__ unsigned short XTh[64][68];
  __shared__ unsigned short XTl[64][68];

  const int b = blockIdx.x;
  const int t = threadIdx.x;
  const int lane = t & 63;
  const int w = t >> 6;

  float* __restrict__ slot = outbuf + (size_t)b * SLOT;
  const unsigned short* __restrict__ slotU = (const unsigned short*)slot;

  const int frow = lane & 15;
  const int fk = (lane >> 4) * 8;

  // A-operand fragments straight from global: planar Th/Tl rows
  s16x8 tah[2], tal[2];
#pragma unroll
  for (int ks = 0; ks < 2; ++ks) {
    tah[ks] = *(const s16x8*)&slotU[(16 * w + frow) * 64 + ks * 32 + fk];
    tal[ks] = *(const s16x8*)&slotU[4096 + (16 * w + frow) * 64 + ks * 32 + fk];
  }
  __syncthreads();   // vmcnt drained at barrier: T loads landed before any store

  const float* __restrict__ X = x + (size_t)b * SLOT;
  const int lrow4 = (t >> 4) * 4;
  const int lcol4 = (t & 15) * 4;

  for (int ch = 0; ch < 8; ++ch) {
    if (ch) __syncthreads();             // protect XT from prev-chunk readers
    float vr[4][4];
#pragma unroll
    for (int p = 0; p < 4; ++p) {
      const f32x4 v = *(const f32x4*)(X + (size_t)(lrow4 + p) * NCOL + ch * 64 + lcol4);
      vr[p][0] = v[0]; vr[p][1] = v[1]; vr[p][2] = v[2]; vr[p][3] = v[3];
    }
#pragma unroll
    for (int jj = 0; jj < 4; ++jj) {
      u16x4 hv, lv;
#pragma unroll
      for (int p = 0; p < 4; ++p) {
        const unsigned short h = bf16h(vr[p][jj]);
        hv[p] = h;
        lv[p] = bf16h(vr[p][jj] - bf16f(h));
      }
      *(u16x4*)&XTh[lcol4 + jj][lrow4] = hv;
      *(u16x4*)&XTl[lcol4 + jj][lrow4] = lv;
    }
    __syncthreads();

    f32x4 oacc[4];
#pragma unroll
    for (int q = 0; q < 4; ++q) { oacc[q][0] = 0.f; oacc[q][1] = 0.f; oacc[q][2] = 0.f; oacc[q][3] = 0.f; }

#pragma unroll
    for (int ks = 0; ks < 2; ++ks) {
      const int kc = ks * 32 + fk;
#pragma unroll
      for (int ct = 0; ct < 4; ++ct) {
        const s16x8 xbh = ld8(&XTh[ct * 16 + frow][kc]);
        const s16x8 xbl = ld8(&XTl[ct * 16 + frow][kc]);
        oacc[ct] = __builtin_amdgcn_mfma_f32_16x16x32_bf16(tah[ks], xbh, oacc[ct], 0, 0, 0);
        oacc[ct] = __builtin_amdgcn_mfma_f32_16x16x32_bf16(tah[ks], xbl, oacc[ct], 0, 0, 0);
        oacc[ct] = __builtin_amdgcn_mfma_f32_16x16x32_bf16(tal[ks], xbh, oacc[ct], 0, 0, 0);
      }
    }

    const int drow = (lane >> 4) * 4;
    const int dcol = lane & 15;
#pragma unroll
    for (int ct = 0; ct < 4; ++ct)
#pragma unroll
      for (int rr = 0; rr < 4; ++rr)
        slot[(size_t)(16 * w + drow + rr) * NCOL + ch * 64 + ct * 16 + dcol] = oacc[ct][rr];
  }
}

extern "C" void kernel_launch(void* const* d_in, const int* in_sizes, int n_in,
                              void* d_out, int out_size, void* d_ws, size_t ws_size,
                              hipStream_t stream) {
  const float* x = (const float*)d_in[0];
  float* out = (float*)d_out;
  gs_gram_kernel<<<NBATCH, 256, 0, stream>>>(x, out);
  gs_solve_kernel<<<NBATCH, 64, 0, stream>>>(out);
  gs_apply_kernel<<<NBATCH, 256, 0, stream>>>(x, out);
}

// Round 16
// 103.924 us; speedup vs baseline: 7.8783x; 3.5817x over previous
//
#include <hip/hip_runtime.h>
#include <hip/hip_bf16.h>
#include <cmath>

typedef __attribute__((ext_vector_type(4))) float f32x4;
typedef __attribute__((ext_vector_type(8))) short s16x8;
typedef __attribute__((ext_vector_type(4))) short s16x4;
typedef __attribute__((ext_vector_type(4))) unsigned short u16x4;

static constexpr int NCOL = 512;    // L
static constexpr int NBATCH = 1024; // 32*32
static constexpr int SLOT = 64 * NCOL;     // floats per batch slot
static constexpr int GOFF = 16384;         // G region: floats [16384, 20480)

__device__ inline unsigned short bf16h(float f) {
  return __builtin_bit_cast(unsigned short, __float2bfloat16(f));
}
__device__ inline float bf16f(unsigned short h) {
  unsigned u = ((unsigned)h) << 16;
  return __builtin_bit_cast(float, u);
}

// 8B-aligned s16x8 load (XT rows at stride 68 ushorts are only 8B-aligned)
__device__ inline s16x8 ld8(const unsigned short* p) {
  const s16x4 a = *(const s16x4*)(p);
  const s16x4 b = *(const s16x4*)(p + 4);
  s16x8 r;
  r[0]=a[0]; r[1]=a[1]; r[2]=a[2]; r[3]=a[3];
  r[4]=b[0]; r[5]=b[1]; r[6]=b[2]; r[7]=b[3];
  return r;
}

// Kernel 1: per-batch G = X X^T via bf16 hi/lo MFMA.  Lean (18.4 KB LDS,
// ~60 VGPR -> 8 blocks/CU).  G accumulators store to the slot's G region.
__global__ __launch_bounds__(256) void gs_gram_kernel(const float* __restrict__ x,
                                                      float* __restrict__ outbuf)
{
  __shared__ unsigned short Hs[64][72];
  __shared__ unsigned short Ls[64][72];

  const int b = blockIdx.x;
  const int t = threadIdx.x;
  const int lane = t & 63;
  const int w = t >> 6;

  const float* __restrict__ X = x + (size_t)b * SLOT;

  f32x4 acc[4];
#pragma unroll
  for (int j = 0; j < 4; ++j) { acc[j][0] = 0.f; acc[j][1] = 0.f; acc[j][2] = 0.f; acc[j][3] = 0.f; }

  const int lrow = t >> 4;               // 0..15
  const int lcol = (t & 15) * 4;
  const int frow = lane & 15;
  const int fk   = (lane >> 4) * 8;

  for (int ch = 0; ch < 8; ++ch) {
    __syncthreads();
#pragma unroll
    for (int p = 0; p < 4; ++p) {
      const int r = lrow + 16 * p;
      const f32x4 v = *(const f32x4*)(X + (size_t)r * NCOL + ch * 64 + lcol);
      u16x4 hv, lv;
#pragma unroll
      for (int j = 0; j < 4; ++j) {
        const unsigned short h = bf16h(v[j]);
        hv[j] = h;
        lv[j] = bf16h(v[j] - bf16f(h));
      }
      *(u16x4*)&Hs[r][lcol] = hv;
      *(u16x4*)&Ls[r][lcol] = lv;
    }
    __syncthreads();
#pragma unroll
    for (int s = 0; s < 2; ++s) {
      const int kc = s * 32 + fk;
      const s16x8 ha = *(const s16x8*)&Hs[16 * w + frow][kc];
      const s16x8 la = *(const s16x8*)&Ls[16 * w + frow][kc];
#pragma unroll
      for (int bt = 0; bt < 4; ++bt) {
        const s16x8 hb = *(const s16x8*)&Hs[16 * bt + frow][kc];
        const s16x8 lb = *(const s16x8*)&Ls[16 * bt + frow][kc];
        acc[bt] = __builtin_amdgcn_mfma_f32_16x16x32_bf16(ha, hb, acc[bt], 0, 0, 0);
        acc[bt] = __builtin_amdgcn_mfma_f32_16x16x32_bf16(ha, lb, acc[bt], 0, 0, 0);
        acc[bt] = __builtin_amdgcn_mfma_f32_16x16x32_bf16(la, hb, acc[bt], 0, 0, 0);
      }
    }
  }

  // C/D layout: col = lane&15, row = (lane>>4)*4 + reg
  float* __restrict__ Gs = outbuf + (size_t)b * SLOT + GOFF;
  const int drow = (lane >> 4) * 4;
  const int dcol = lane & 15;
#pragma unroll
  for (int bt = 0; bt < 4; ++bt)
#pragma unroll
    for (int rr = 0; rr < 4; ++rr)
      Gs[(16 * w + drow + rr) * 64 + 16 * bt + dcol] = acc[bt][rr];
}

// Kernel 2: one wave per batch, TWO-PASS solve (round-9 proven shape —
// wr[] dies before ti[] is allocated, so register peak stays ~130; the
// fused single-pass variant (R15) and all-shuffle variants (R13/14) all
// spilled to 256 VGPR).  Cs in LDS: column k written at step k, row k
// read back as uniform broadcasts.  Emits T = diag(1/sqrt(n))*(I+C)^{-1}
// planar bf16 hi/lo to the slot head via in-LDS transpose.
__global__ __launch_bounds__(64) void gs_solve_kernel(float* __restrict__ outbuf)
{
  __shared__ float Cs[64][68];
  __shared__ float ISN[64];

  const int b = blockIdx.x;
  const int j = threadIdx.x;             // lane = row (LDL) / column (TI)
  float* __restrict__ slot = outbuf + (size_t)b * SLOT;
  const float* __restrict__ Gs = slot + GOFF;

  // W-row j of G into registers
  float wr[64];
#pragma unroll
  for (int c = 0; c < 16; ++c) {
    const f32x4 v = *(const f32x4*)(Gs + j * 64 + 4 * c);
    wr[4 * c + 0] = v[0]; wr[4 * c + 1] = v[1]; wr[4 * c + 2] = v[2]; wr[4 * c + 3] = v[3];
  }

  // LDL: W[i][k] = G[i][k] - sum_{m<k} Cs[k][m]*W[i][m], Cs[i][k]=W[i][k]/n_k
  {
    const float nk = __shfl(wr[0], 0);
    const float inv = 1.0f / nk;
    Cs[j][0] = wr[0] * inv;
    if (j == 0) ISN[0] = sqrtf(inv);
  }
#pragma unroll
  for (int k = 1; k < 64; ++k) {
    float a0 = 0.f, a1 = 0.f, a2 = 0.f, a3 = 0.f;
    const int K4 = k >> 2;
#pragma unroll
    for (int m4 = 0; m4 < K4; ++m4) {
      const f32x4 c4 = *(const f32x4*)&Cs[k][4 * m4];   // uniform broadcast
      a0 += c4[0] * wr[4 * m4 + 0];
      a1 += c4[1] * wr[4 * m4 + 1];
      a2 += c4[2] * wr[4 * m4 + 2];
      a3 += c4[3] * wr[4 * m4 + 3];
    }
#pragma unroll
    for (int m = 4 * K4; m < k; ++m) a0 += Cs[k][m] * wr[m];
    wr[k] -= (a0 + a1) + (a2 + a3);
    const float nk = __shfl(wr[k], k);
    const float inv = 1.0f / nk;
    Cs[j][k] = wr[k] * inv;
    if (j == 0) ISN[k] = sqrtf(inv);
  }

  // TI: lane j owns column j in registers.  ti[i] = d(i,j) - sum Cs[i][m]*ti[m]
  float ti[64];
  ti[0] = (j == 0) ? 1.0f : 0.0f;
#pragma unroll
  for (int i = 1; i < 64; ++i) {
    float a0 = 0.f, a1 = 0.f, a2 = 0.f, a3 = 0.f;
    const int I4 = i >> 2;
#pragma unroll
    for (int m4 = 0; m4 < I4; ++m4) {
      const f32x4 c4 = *(const f32x4*)&Cs[i][4 * m4];   // uniform broadcast
      a0 += c4[0] * ti[4 * m4 + 0];
      a1 += c4[1] * ti[4 * m4 + 1];
      a2 += c4[2] * ti[4 * m4 + 2];
      a3 += c4[3] * ti[4 * m4 + 3];
    }
#pragma unroll
    for (int m = 4 * I4; m < i; ++m) a0 += Cs[i][m] * ti[m];
    ti[i] = ((i == j) ? 1.0f : 0.0f) - ((a0 + a1) + (a2 + a3));
  }

  // transpose T into LDS (overlay over dead Cs): lane j writes column j.
  unsigned short* __restrict__ TL = (unsigned short*)&Cs[0][0]; // 2x 64x64 u16
#pragma unroll
  for (int i = 0; i < 64; ++i) {
    const float tf = ISN[i] * ti[i];
    const unsigned short h = bf16h(tf);
    TL[i * 64 + j] = h;                            // Th plane
    TL[4096 + i * 64 + j] = bf16h(tf - bf16f(h));  // Tl plane
  }
  __syncthreads();
  // coalesced 16 KB copy to the slot head
  const unsigned int* __restrict__ TL32 = (const unsigned int*)TL;
  unsigned int* __restrict__ slotT = (unsigned int*)slot;
#pragma unroll
  for (int q = 0; q < 64; ++q) slotT[j + 64 * q] = TL32[j + 64 * q];
}

// Kernel 3: out = T * X per batch, pure MFMA.  T fragments loaded DIRECTLY
// from global (planar layout; 4x16B per thread, L3-hot).  17.4 KB LDS.
__global__ __launch_bounds__(256) void gs_apply_kernel(const float* __restrict__ x,
                                                       float* __restrict__ outbuf)
{
  __shared__ unsigned short XTh[64][68];
  __shared__ unsigned short XTl[64][68];

  const int b = blockIdx.x;
  const int t = threadIdx.x;
  const int lane = t & 63;
  const int w = t >> 6;

  float* __restrict__ slot = outbuf + (size_t)b * SLOT;
  const unsigned short* __restrict__ slotU = (const unsigned short*)slot;

  const int frow = lane & 15;
  const int fk = (lane >> 4) * 8;

  // A-operand fragments straight from global: planar Th/Tl rows
  s16x8 tah[2], tal[2];
#pragma unroll
  for (int ks = 0; ks < 2; ++ks) {
    tah[ks] = *(const s16x8*)&slotU[(16 * w + frow) * 64 + ks * 32 + fk];
    tal[ks] = *(const s16x8*)&slotU[4096 + (16 * w + frow) * 64 + ks * 32 + fk];
  }
  __syncthreads();   // vmcnt drained at barrier: T loads landed before any store

  const float* __restrict__ X = x + (size_t)b * SLOT;
  const int lrow4 = (t >> 4) * 4;
  const int lcol4 = (t & 15) * 4;

  for (int ch = 0; ch < 8; ++ch) {
    if (ch) __syncthreads();             // protect XT from prev-chunk readers
    float vr[4][4];
#pragma unroll
    for (int p = 0; p < 4; ++p) {
      const f32x4 v = *(const f32x4*)(X + (size_t)(lrow4 + p) * NCOL + ch * 64 + lcol4);
      vr[p][0] = v[0]; vr[p][1] = v[1]; vr[p][2] = v[2]; vr[p][3] = v[3];
    }
#pragma unroll
    for (int jj = 0; jj < 4; ++jj) {
      u16x4 hv, lv;
#pragma unroll
      for (int p = 0; p < 4; ++p) {
        const unsigned short h = bf16h(vr[p][jj]);
        hv[p] = h;
        lv[p] = bf16h(vr[p][jj] - bf16f(h));
      }
      *(u16x4*)&XTh[lcol4 + jj][lrow4] = hv;
      *(u16x4*)&XTl[lcol4 + jj][lrow4] = lv;
    }
    __syncthreads();

    f32x4 oacc[4];
#pragma unroll
    for (int q = 0; q < 4; ++q) { oacc[q][0] = 0.f; oacc[q][1] = 0.f; oacc[q][2] = 0.f; oacc[q][3] = 0.f; }

#pragma unroll
    for (int ks = 0; ks < 2; ++ks) {
      const int kc = ks * 32 + fk;
#pragma unroll
      for (int ct = 0; ct < 4; ++ct) {
        const s16x8 xbh = ld8(&XTh[ct * 16 + frow][kc]);
        const s16x8 xbl = ld8(&XTl[ct * 16 + frow][kc]);
        oacc[ct] = __builtin_amdgcn_mfma_f32_16x16x32_bf16(tah[ks], xbh, oacc[ct], 0, 0, 0);
        oacc[ct] = __builtin_amdgcn_mfma_f32_16x16x32_bf16(tah[ks], xbl, oacc[ct], 0, 0, 0);
        oacc[ct] = __builtin_amdgcn_mfma_f32_16x16x32_bf16(tal[ks], xbh, oacc[ct], 0, 0, 0);
      }
    }

    const int drow = (lane >> 4) * 4;
    const int dcol = lane & 15;
#pragma unroll
    for (int ct = 0; ct < 4; ++ct)
#pragma unroll
      for (int rr = 0; rr < 4; ++rr)
        slot[(size_t)(16 * w + drow + rr) * NCOL + ch * 64 + ct * 16 + dcol] = oacc[ct][rr];
  }
}

extern "C" void kernel_launch(void* const* d_in, const int* in_sizes, int n_in,
                              void* d_out, int out_size, void* d_ws, size_t ws_size,
                              hipStream_t stream) {
  const float* x = (const float*)d_in[0];
  float* out = (float*)d_out;
  gs_gram_kernel<<<NBATCH, 256, 0, stream>>>(x, out);
  gs_solve_kernel<<<NBATCH, 64, 0, stream>>>(out);
  gs_apply_kernel<<<NBATCH, 256, 0, stream>>>(x, out);
}